// Round 1
// baseline (6730.274 us; speedup 1.0000x reference)
//
#include <hip/hip_runtime.h>
#include <hip/hip_bf16.h>
#include <stdint.h>

#define BATCH 64
#define SLEN 128
#define TLEN 128
#define ENCD 512
#define DECD 512
#define EMBD 256
#define VOC  8000
#define HE   20
#define KX   1280      // EMB + DEC + ENC
#define NPAD 8064      // VOC padded to 63*128

typedef __attribute__((ext_vector_type(8))) short short8;
typedef __attribute__((ext_vector_type(4))) float f32x4;
typedef _Float16 h2 __attribute__((ext_vector_type(2)));

// ---------- helpers ----------
__device__ inline unsigned short f2bf(float f) {
  union { float f; uint32_t u; } v; v.f = f;
  uint32_t r = v.u + 0x7fff + ((v.u >> 16) & 1);
  return (unsigned short)(r >> 16);
}

__device__ inline uint32_t pkh2(float a, float b) {
  union { h2 h; uint32_t u; } v;
  v.h = h2{(_Float16)a, (_Float16)b};
  return v.u;
}

__device__ inline float fdot2(uint32_t a, uint32_t b, float c) {
#if __has_builtin(__builtin_amdgcn_fdot2)
  union { uint32_t u; h2 h; } x, y; x.u = a; y.u = b;
  return __builtin_amdgcn_fdot2(x.h, y.h, c, false);
#else
  union { uint32_t u; h2 h; } x, y; x.u = a; y.u = b;
  return c + (float)x.h[0] * (float)y.h[0] + (float)x.h[1] * (float)y.h[1];
#endif
}

__device__ inline float eluf(float x) { return x > 0.f ? x : (expf(x) - 1.f); }

typedef const __attribute__((address_space(1))) unsigned int* gptr_t;
typedef __attribute__((address_space(3))) unsigned int* lptr_t;
__device__ inline void gload16(const void* g, void* l) {
  __builtin_amdgcn_global_load_lds((gptr_t)g, (lptr_t)l, 16, 0, 0);
}

// ---------- kernel 1a: E1[b*S+s][h] = sum_e enc[b,s,e] * We1[e,h] ----------
__global__ __launch_bounds__(256) void k_e1(const float* __restrict__ enc,
                                            const float* __restrict__ We1,
                                            float* __restrict__ E1) {
  __shared__ float rowbuf[4][ENCD];
  __shared__ float part[4][HE][2];
  int r0 = blockIdx.x * 4;
  int tid = threadIdx.x;
  for (int i = tid; i < 4 * ENCD; i += 256) {
    int rl = i >> 9, e = i & 511;
    rowbuf[rl][e] = enc[(size_t)(r0 + rl) * ENCD + e];
  }
  __syncthreads();
  if (tid < 160) {
    int kg = tid / 80, rem = tid % 80, rl = rem / 20, h = rem % 20;
    float acc = 0.f;
    for (int k = kg * 256; k < kg * 256 + 256; ++k)
      acc += rowbuf[rl][k] * We1[k * HE + h];
    part[rl][h][kg] = acc;
  }
  __syncthreads();
  if (tid < 80) {
    int rl = tid / 20, h = tid % 20;
    E1[(size_t)(r0 + rl) * HE + h] = part[rl][h][0] + part[rl][h][1];
  }
}

// ---------- kernel 1b: W_out [1280][8000] f32 -> WoT [8064][1280] bf16 (pad 0) ----------
__global__ __launch_bounds__(256) void k_tr_wout(const float* __restrict__ Wo,
                                                 unsigned short* __restrict__ WoT) {
  __shared__ float tile[64][65];
  int n0 = blockIdx.x * 64, k0 = blockIdx.y * 64;
  int tid = threadIdx.x;
  for (int i = tid; i < 4096; i += 256) {
    int kk = i >> 6, nn = i & 63;
    int n = n0 + nn;
    tile[kk][nn] = (n < VOC) ? Wo[(size_t)(k0 + kk) * VOC + n] : 0.f;
  }
  __syncthreads();
  for (int i = tid; i < 4096; i += 256) {
    int nn = i >> 6, kk = i & 63;
    WoT[(size_t)(n0 + nn) * KX + k0 + kk] = f2bf(tile[kk][nn]);
  }
}

// ---------- kernel 1c: W_rnn [1280][512] f32 -> WrT [512][1280] f16 ----------
__global__ __launch_bounds__(256) void k_tr_wrnn(const float* __restrict__ Wr,
                                                 unsigned short* __restrict__ WrT) {
  __shared__ float tile[64][65];
  int n0 = blockIdx.x * 64, k0 = blockIdx.y * 64;
  int tid = threadIdx.x;
  for (int i = tid; i < 4096; i += 256) {
    int kk = i >> 6, nn = i & 63;
    tile[kk][nn] = Wr[(size_t)(k0 + kk) * DECD + n0 + nn];
  }
  __syncthreads();
  for (int i = tid; i < 4096; i += 256) {
    int nn = i >> 6, kk = i & 63;
    union { _Float16 h; unsigned short u; } c; c.h = (_Float16)tile[kk][nn];
    WrT[(size_t)(n0 + nn) * KX + k0 + kk] = c.u;
  }
}

// ---------- kernel 1d: enc [b][s][e] f32 -> encT [b][e][s] f16 ----------
__global__ __launch_bounds__(256) void k_tr_enc(const float* __restrict__ enc,
                                                unsigned short* __restrict__ encT) {
  __shared__ float tile[64][65];
  int b = blockIdx.x, e0 = blockIdx.y * 64, s0 = blockIdx.z * 64;
  int tid = threadIdx.x;
  const float* eb = enc + (size_t)b * SLEN * ENCD;
  for (int i = tid; i < 4096; i += 256) {
    int ss = i >> 6, ee = i & 63;
    tile[ss][ee] = eb[(size_t)(s0 + ss) * ENCD + e0 + ee];
  }
  __syncthreads();
  unsigned short* ob = encT + (size_t)b * ENCD * SLEN;
  for (int i = tid; i < 4096; i += 256) {
    int ee = i >> 6, ss = i & 63;
    union { _Float16 h; unsigned short u; } c; c.h = (_Float16)tile[ss][ee];
    ob[(size_t)(e0 + ee) * SLEN + s0 + ss] = c.u;
  }
}

// ---------- kernel 1e: X[t*B+b][0:256] = bf16(emb[lc]) ----------
__global__ __launch_bounds__(256) void k_lc(const int* __restrict__ ro,
                                            const float* __restrict__ emb,
                                            unsigned short* __restrict__ X) {
  int r = blockIdx.x;           // 0..8191 ; r = t*B + b
  int t = r >> 6, b = r & 63;
  int lc = (t == 0) ? 0 : ro[b * TLEN + t - 1];
  lc = ((lc % VOC) + VOC) % VOC;
  X[(size_t)r * KX + threadIdx.x] = f2bf(emb[(size_t)lc * EMBD + threadIdx.x]);
}

// ---------- kernel 2: sequential recurrence, 1 block per batch element ----------
__global__ __launch_bounds__(512) void k_recur(
    const int* __restrict__ ro,
    const float* __restrict__ We1,     // [1024][20]
    const float* __restrict__ be1,     // [20]
    const float* __restrict__ We2,     // [20]
    const float* __restrict__ be2,     // [1]
    const float* __restrict__ emb,     // [V][256]
    const float* __restrict__ brnn_g,  // [512]
    const unsigned short* __restrict__ WrT,   // [512][1280] f16
    const unsigned short* __restrict__ encT,  // [64][512][128] f16
    const float* __restrict__ E1g,     // [64][128][20]
    unsigned short* __restrict__ X,    // [8192][1280] bf16
    float* __restrict__ wout)          // [64][128][128]
{
  __shared__ float hidA[DECD], hidB[DECD], ctx[DECD];
  __shared__ float E1r[SLEN][HE];
  __shared__ unsigned short w1dT[HE][DECD];  // f16 bits of W_e1[512:][h] transposed
  __shared__ float edec[HE];
  __shared__ float sc[8][HE];
  __shared__ float ew[SLEN], wq[SLEN];
  __shared__ float brnn[DECD];
  __shared__ float w2[HE];
  __shared__ float misc[2];
  __shared__ __align__(16) uint32_t xpair[KX / 2];   // 640 f16-pairs
  __shared__ __align__(16) uint32_t wpair[SLEN / 2]; // 64

  int b = blockIdx.x, tid = threadIdx.x;

  for (int i = tid; i < SLEN * HE; i += 512) E1r[i / HE][i % HE] = E1g[(size_t)b * SLEN * HE + i];
  for (int i = tid; i < HE * DECD; i += 512) {
    int h = i >> 9, k = i & 511;
    union { _Float16 hh; unsigned short u; } c; c.hh = (_Float16)We1[(size_t)(ENCD + k) * HE + h];
    w1dT[h][k] = c.u;
  }
  for (int i = tid; i < DECD; i += 512) { brnn[i] = brnn_g[i]; hidA[i] = 0.f; }
  if (tid < HE) w2[tid] = We2[tid];
  if (tid == 0) misc[0] = be2[0];
  __syncthreads();

  const unsigned short* encTb = encT + (size_t)b * ENCD * SLEN;
  float* hcur = hidA; float* hnxt = hidB;

  for (int t = 0; t < TLEN; ++t) {
    int lc = (t == 0) ? 0 : ro[b * TLEN + t - 1];
    lc = ((lc % VOC) + VOC) % VOC;
    unsigned short* xr = X + ((size_t)t * BATCH + b) * KX;

    // ---- e_dec[h] = b_e1[h] + hid . W_e1_dec[:,h]
    if (tid < 256) {
      int h = tid & 31, kg = tid >> 5;
      if (h < HE) {
        float acc = 0.f;
        const unsigned short* wr = &w1dT[h][kg * 64];
        const float* hp = &hcur[kg * 64];
        for (int k = 0; k < 64; ++k) {
          union { unsigned short u; _Float16 hh; } c; c.u = wr[k];
          acc += hp[k] * (float)c.hh;
        }
        sc[kg][h] = acc;
      }
    }
    __syncthreads();
    if (tid < HE) {
      float a = be1[tid];
      for (int kg = 0; kg < 8; ++kg) a += sc[kg][tid];
      edec[tid] = a;
    }
    __syncthreads();

    // ---- scores: ew[s] = exp(elu(sum_h elu(E1+edec)[h]*We2[h] + b_e2))
    if (tid < 256) {
      int s = tid >> 1, hh = (tid & 1) * 10;
      float p = 0.f;
      for (int h = hh; h < hh + 10; ++h)
        p += eluf(E1r[s][h] + edec[h]) * w2[h];
      p += __shfl_xor(p, 1);
      if ((tid & 1) == 0) ew[s] = expf(eluf(p + misc[0]));
    }
    __syncthreads();
    if (tid < 64) {
      float v = ew[tid] + ew[tid + 64];
      for (int o = 32; o; o >>= 1) v += __shfl_xor(v, o);
      if (tid == 0) misc[1] = 1.f / v;
    }
    __syncthreads();
    if (tid < SLEN) {
      float w = ew[tid] * misc[1];
      wq[tid] = w;
      wout[((size_t)b * TLEN + t) * SLEN + tid] = w;
    }
    __syncthreads();
    if (tid < SLEN / 2) wpair[tid] = pkh2(wq[2 * tid], wq[2 * tid + 1]);
    __syncthreads();

    // ---- context[e] = sum_s w[s]*enc[b,s,e]  (f16 dot2 over encT rows)
    {
      const uint4* wp4 = (const uint4*)wpair;   // 16
      for (int e = tid; e < DECD; e += 512) {
        const uint4* ep4 = (const uint4*)(encTb + (size_t)e * SLEN);
        float acc = 0.f;
        for (int c = 0; c < 16; ++c) {
          uint4 E = ep4[c]; uint4 W = wp4[c];
          acc = fdot2(E.x, W.x, acc);
          acc = fdot2(E.y, W.y, acc);
          acc = fdot2(E.z, W.z, acc);
          acc = fdot2(E.w, W.w, acc);
        }
        ctx[e] = acc;
        xr[768 + e] = f2bf(acc);
      }
    }
    __syncthreads();

    // ---- pack x = [emb[lc](256) | hid(512) | ctx(512)] as f16 pairs
    {
      const float* er = emb + (size_t)lc * EMBD;
      for (int p = tid; p < KX / 2; p += 512) {
        float a, c;
        if (p < 128)      { a = er[2 * p];         c = er[2 * p + 1]; }
        else if (p < 384) { int k = 2 * p - 256;   a = hcur[k]; c = hcur[k + 1]; }
        else              { int k = 2 * p - 768;   a = ctx[k];  c = ctx[k + 1]; }
        xpair[p] = pkh2(a, c);
      }
    }
    __syncthreads();

    // ---- RNN: hnxt[n] = elu(b_rnn[n] + x . W_rnn[:,n]) ; one col per thread
    {
      int n = tid;
      const uint4* wv = (const uint4*)(WrT + (size_t)n * KX);
      const uint4* xp4 = (const uint4*)xpair;   // 160
      float a = brnn[n];
      for (int c = 0; c < 160; ++c) {
        uint4 xv = xp4[c];
        uint4 u = wv[c];
        a = fdot2(u.x, xv.x, a);
        a = fdot2(u.y, xv.y, a);
        a = fdot2(u.z, xv.z, a);
        a = fdot2(u.w, xv.w, a);
      }
      a = eluf(a);
      hnxt[n] = a;
      xr[256 + n] = f2bf(a);
    }
    __syncthreads();
    { float* tmp = hcur; hcur = hnxt; hnxt = tmp; }
  }
}

// ---------- kernel 3: out = elu(X @ W_out^T^T + b_out), M=8192 N=8000 K=1280 ----------
#define BM 128
#define BN 128
#define BK 64

__global__ __launch_bounds__(256) void k_gemm(
    const unsigned short* __restrict__ Xb,   // [8192][1280] bf16
    const unsigned short* __restrict__ WoT,  // [8064][1280] bf16
    const float* __restrict__ bout,          // [8000]
    float* __restrict__ out)                 // [64][128][8000]
{
  __shared__ __align__(16) unsigned short As[BM * BK];
  __shared__ __align__(16) unsigned short Bs[BN * BK];
  int bx = blockIdx.x;   // n tile 0..62
  int by = blockIdx.y;   // m tile 0..63
  int tid = threadIdx.x;
  int wid = tid >> 6, lane = tid & 63;
  int wr = wid >> 1, wc = wid & 1;

  f32x4 acc[4][4];
  for (int i = 0; i < 4; ++i)
    for (int j = 0; j < 4; ++j) acc[i][j] = (f32x4)0.f;

  const unsigned short* Abase = Xb + (size_t)by * BM * KX;
  const unsigned short* Bbase = WoT + (size_t)bx * BN * KX;

  for (int kt = 0; kt < KX / BK; ++kt) {
    // stage both tiles: 1024 16B-chunks each; LDS linear, source XOR-pre-swizzled
    for (int j = 0; j < 4; ++j) {
      int c = tid + j * 256;
      int r = c >> 3, c16 = c & 7;
      int sk = c16 ^ (r & 7);
      gload16(Abase + (size_t)r * KX + kt * BK + sk * 8, (char*)As + c * 16);
      gload16(Bbase + (size_t)r * KX + kt * BK + sk * 8, (char*)Bs + c * 16);
    }
    __syncthreads();   // drains vmcnt before barrier (compiler-inserted)
    for (int ks = 0; ks < 2; ++ks) {
      short8 af[4], bf[4];
      int kc = ks * 4 + (lane >> 4);
      for (int i = 0; i < 4; ++i) {
        int r = wr * 64 + i * 16 + (lane & 15);
        af[i] = *(const short8*)((const char*)As + r * 128 + ((kc ^ (r & 7)) * 16));
      }
      for (int j = 0; j < 4; ++j) {
        int r = wc * 64 + j * 16 + (lane & 15);
        bf[j] = *(const short8*)((const char*)Bs + r * 128 + ((kc ^ (r & 7)) * 16));
      }
      for (int i = 0; i < 4; ++i)
        for (int j = 0; j < 4; ++j)
          acc[i][j] = __builtin_amdgcn_mfma_f32_16x16x32_bf16(af[i], bf[j], acc[i][j], 0, 0, 0);
    }
    __syncthreads();
  }

  // epilogue: bias + elu, remap row t*64+b -> out[b][t][:]
  int rl = lane >> 4, cl = lane & 15;
  for (int j = 0; j < 4; ++j) {
    int gn = bx * BN + wc * 64 + j * 16 + cl;
    if (gn >= VOC) continue;
    float bv = bout[gn];
    for (int i = 0; i < 4; ++i) {
      for (int q = 0; q < 4; ++q) {
        int gm = by * BM + wr * 64 + i * 16 + rl * 4 + q;
        int tt = gm >> 6, bb = gm & 63;
        float v = acc[i][j][q] + bv;
        v = v > 0.f ? v : (expf(v) - 1.f);
        out[((size_t)bb * TLEN + tt) * VOC + gn] = v;
      }
    }
  }
}

// ---------- launch ----------
extern "C" void kernel_launch(void* const* d_in, const int* in_sizes, int n_in,
                              void* d_out, int out_size, void* d_ws, size_t ws_size,
                              hipStream_t stream) {
  const float* enc  = (const float*)d_in[0];
  const int*   ro   = (const int*)d_in[1];
  const float* We1  = (const float*)d_in[2];
  const float* be1  = (const float*)d_in[3];
  const float* We2  = (const float*)d_in[4];
  const float* be2  = (const float*)d_in[5];
  const float* emb  = (const float*)d_in[6];
  const float* Wr   = (const float*)d_in[7];
  const float* brnn = (const float*)d_in[8];
  const float* Wo   = (const float*)d_in[9];
  const float* bo   = (const float*)d_in[10];

  char* ws = (char*)d_ws;
  unsigned short* X    = (unsigned short*)(ws);                  // 8192*1280*2   = 20,971,520
  unsigned short* WoT  = (unsigned short*)(ws + 20971520);       // 8064*1280*2   = 20,643,840
  unsigned short* WrT  = (unsigned short*)(ws + 41615360);       // 512*1280*2    =  1,310,720
  unsigned short* encT = (unsigned short*)(ws + 42926080);       // 64*512*128*2  =  8,388,608
  float*          E1   = (float*)(ws + 51314688);                // 64*128*20*4   =    655,360

  float* outs = (float*)d_out;
  float* wout = (float*)d_out + (size_t)BATCH * TLEN * VOC;

  k_e1    <<<dim3(2048),      256, 0, stream>>>(enc, We1, E1);
  k_tr_wout<<<dim3(126, 20),  256, 0, stream>>>(Wo, WoT);
  k_tr_wrnn<<<dim3(8, 20),    256, 0, stream>>>(Wr, WrT);
  k_tr_enc<<<dim3(64, 8, 2),  256, 0, stream>>>(enc, encT);
  k_lc    <<<dim3(8192),      256, 0, stream>>>(ro, emb, X);
  k_recur <<<dim3(64),        512, 0, stream>>>(ro, We1, be1, We2, be2, emb, brnn,
                                                WrT, encT, E1, X, wout);
  k_gemm  <<<dim3(63, 64),    256, 0, stream>>>(X, WoT, bo, outs);
  (void)in_sizes; (void)n_in; (void)out_size; (void)ws_size;
}

// Round 2
// 2016.977 us; speedup vs baseline: 3.3368x; 3.3368x over previous
//
#include <hip/hip_runtime.h>
#include <hip/hip_bf16.h>
#include <stdint.h>

#define BATCH 64
#define SLEN 128
#define TLEN 128
#define ENCD 512
#define DECD 512
#define EMBD 256
#define VOC  8000
#define HE   20
#define KX   1280      // EMB + DEC + ENC
#define NPAD 8064      // VOC padded to 63*128

typedef __attribute__((ext_vector_type(8))) short short8;
typedef __attribute__((ext_vector_type(8))) _Float16 half8v;
typedef __attribute__((ext_vector_type(4))) float f32x4;
typedef _Float16 h2 __attribute__((ext_vector_type(2)));

// ---------- helpers ----------
__device__ inline unsigned short f2bf(float f) {
  union { float f; uint32_t u; } v; v.f = f;
  uint32_t r = v.u + 0x7fff + ((v.u >> 16) & 1);
  return (unsigned short)(r >> 16);
}
__device__ inline unsigned short f16bits(float f) {
  union { _Float16 h; unsigned short u; } c; c.h = (_Float16)f; return c.u;
}
__device__ inline uint32_t pkh2(float a, float b) {
  union { h2 h; uint32_t u; } v;
  v.h = h2{(_Float16)a, (_Float16)b};
  return v.u;
}
__device__ inline float fdot2(uint32_t a, uint32_t b, float c) {
#if __has_builtin(__builtin_amdgcn_fdot2)
  union { uint32_t u; h2 h; } x, y; x.u = a; y.u = b;
  return __builtin_amdgcn_fdot2(x.h, y.h, c, false);
#else
  union { uint32_t u; h2 h; } x, y; x.u = a; y.u = b;
  return c + (float)x.h[0] * (float)y.h[0] + (float)x.h[1] * (float)y.h[1];
#endif
}
__device__ inline float eluf(float x) { return x > 0.f ? x : (expf(x) - 1.f); }

typedef const __attribute__((address_space(1))) unsigned int* gptr_t;
typedef __attribute__((address_space(3))) unsigned int* lptr_t;
__device__ inline void gload16(const void* g, void* l) {
  __builtin_amdgcn_global_load_lds((gptr_t)g, (lptr_t)l, 16, 0, 0);
}

// ---------- k_e1: E1[b*S+s][h] = enc[b,s,:] @ We1[0:512,h] ----------
__global__ __launch_bounds__(256) void k_e1(const float* __restrict__ enc,
                                            const float* __restrict__ We1,
                                            float* __restrict__ E1) {
  __shared__ float rowbuf[4][ENCD];
  __shared__ float part[4][HE][2];
  int r0 = blockIdx.x * 4;
  int tid = threadIdx.x;
  for (int i = tid; i < 4 * ENCD; i += 256) {
    int rl = i >> 9, e = i & 511;
    rowbuf[rl][e] = enc[(size_t)(r0 + rl) * ENCD + e];
  }
  __syncthreads();
  if (tid < 160) {
    int kg = tid / 80, rem = tid % 80, rl = rem / 20, h = rem % 20;
    float acc = 0.f;
    for (int k = kg * 256; k < kg * 256 + 256; ++k)
      acc += rowbuf[rl][k] * We1[k * HE + h];
    part[rl][h][kg] = acc;
  }
  __syncthreads();
  if (tid < 80) {
    int rl = tid / 20, h = tid % 20;
    E1[(size_t)(r0 + rl) * HE + h] = part[rl][h][0] + part[rl][h][1];
  }
}

// ---------- k_tr_wout: W_out [1280][8000] f32 -> WoT [8064][1280] bf16 ----------
__global__ __launch_bounds__(256) void k_tr_wout(const float* __restrict__ Wo,
                                                 unsigned short* __restrict__ WoT) {
  __shared__ float tile[64][65];
  int n0 = blockIdx.x * 64, k0 = blockIdx.y * 64;
  int tid = threadIdx.x;
  for (int i = tid; i < 4096; i += 256) {
    int kk = i >> 6, nn = i & 63;
    int n = n0 + nn;
    tile[kk][nn] = (n < VOC) ? Wo[(size_t)(k0 + kk) * VOC + n] : 0.f;
  }
  __syncthreads();
  for (int i = tid; i < 4096; i += 256) {
    int nn = i >> 6, kk = i & 63;
    WoT[(size_t)(n0 + nn) * KX + k0 + kk] = f2bf(tile[kk][nn]);
  }
}

// ---------- k_tr_w: src rows [k0 .. k0+KN) of [*][512] f32 -> dst [512][KN] (fmt1=bf16, fmt0=f16) ----------
__global__ __launch_bounds__(256) void k_tr_w(const float* __restrict__ src,
                                              unsigned short* __restrict__ dst,
                                              int k0, int KN, int fmt) {
  __shared__ float tile[64][65];
  int n0 = blockIdx.x * 64, kt = blockIdx.y * 64;
  int tid = threadIdx.x;
  for (int i = tid; i < 4096; i += 256) {
    int kk = i >> 6, nn = i & 63;
    tile[kk][nn] = src[(size_t)(k0 + kt + kk) * 512 + n0 + nn];
  }
  __syncthreads();
  for (int i = tid; i < 4096; i += 256) {
    int nn = i >> 6, kk = i & 63;
    float v = tile[kk][nn];
    dst[(size_t)(n0 + nn) * KN + kt + kk] = fmt ? f2bf(v) : f16bits(v);
  }
}

// ---------- k_prep_wr: Wr rows 256..768 -> chunked f16 W2[(h*32+kc)*512+n][8] ----------
__global__ __launch_bounds__(256) void k_prep_wr(const float* __restrict__ Wr,
                                                 unsigned short* __restrict__ W2) {
  int i = blockIdx.x * 256 + threadIdx.x;   // 0 .. 262143
  int n = i & 511;
  int j = (i >> 9) & 7;
  int kc = (i >> 12) & 31;
  int h = (i >> 17) & 1;
  int k = h * 256 + kc * 8 + j;
  W2[(((size_t)(h * 32 + kc) * 512) + n) * 8 + j] = f16bits(Wr[(size_t)(256 + k) * 512 + n]);
}

// ---------- k_ench: enc f32 -> f16 flat [8192][512] ----------
__global__ __launch_bounds__(256) void k_ench(const float* __restrict__ enc,
                                              unsigned short* __restrict__ ench) {
  int i = (blockIdx.x * 256 + threadIdx.x) * 4;
  float4 v = *(const float4*)(enc + i);
  ushort4 o = { f16bits(v.x), f16bits(v.y), f16bits(v.z), f16bits(v.w) };
  *(ushort4*)(ench + i) = o;
}

// ---------- k_wh: wout f32 [8192][128] -> f16 ----------
__global__ __launch_bounds__(256) void k_wh(const float* __restrict__ wout,
                                            unsigned short* __restrict__ wh) {
  int i = (blockIdx.x * 256 + threadIdx.x) * 4;
  float4 v = *(const float4*)(wout + i);
  ushort4 o = { f16bits(v.x), f16bits(v.y), f16bits(v.z), f16bits(v.w) };
  *(ushort4*)(wh + i) = o;
}

// ---------- k_tr_encb: enc [b][s][e] f32 -> encTh [b][e][s] f16 ----------
__global__ __launch_bounds__(256) void k_tr_encb(const float* __restrict__ enc,
                                                 unsigned short* __restrict__ encT) {
  __shared__ float tile[64][65];
  int b = blockIdx.x, e0 = blockIdx.y * 64, s0 = blockIdx.z * 64;
  int tid = threadIdx.x;
  const float* eb = enc + (size_t)b * SLEN * ENCD;
  for (int i = tid; i < 4096; i += 256) {
    int ss = i >> 6, ee = i & 63;
    tile[ss][ee] = eb[(size_t)(s0 + ss) * ENCD + e0 + ee];
  }
  __syncthreads();
  unsigned short* ob = encT + (size_t)b * ENCD * SLEN;
  for (int i = tid; i < 4096; i += 256) {
    int ee = i >> 6, ss = i & 63;
    ob[(size_t)(e0 + ee) * SLEN + s0 + ss] = f16bits(tile[ss][ee]);
  }
}

// ---------- k_lc: X[t*B+b][0:256] = bf16(emb[lc]) ----------
__global__ __launch_bounds__(256) void k_lc(const int* __restrict__ ro,
                                            const float* __restrict__ emb,
                                            unsigned short* __restrict__ X) {
  int r = blockIdx.x;           // r = t*B + b
  int t = r >> 6, b = r & 63;
  int lc = (t == 0) ? 0 : ro[b * TLEN + t - 1];
  lc = ((lc % VOC) + VOC) % VOC;
  X[(size_t)r * KX + threadIdx.x] = f2bf(emb[(size_t)lc * EMBD + threadIdx.x]);
}

// ---------- k_gs<MODE>: 128x128xK MFMA GEMM ----------
// MODE 0 (REMB):  A=X bf16 (stride KX, cols 0..256), B=WembT bf16 [512][256] -> Remb f16 [8192][512] (+brnn)
// MODE 1 (ENCWR): A=ench f16 [8192][512], B=WctxT f16 [512][512] -> encW2 chunked f16
// MODE 2 (CTX):   A=wh f16 [8192][128], B=encTh f16 per-batch [512][128] -> X[:,768:1280] bf16
#define BM 128
#define BN 128
#define BK 64

template<int MODE>
__global__ __launch_bounds__(256) void k_gs(
    const unsigned short* __restrict__ A,
    const unsigned short* __restrict__ B,
    const float* __restrict__ bias,
    unsigned short* __restrict__ Cout)
{
  constexpr int As = (MODE == 0) ? KX : (MODE == 1 ? 512 : 128);
  constexpr int Bs = (MODE == 0) ? 256 : (MODE == 1 ? 512 : 128);
  constexpr int KT = (MODE == 0) ? 4 : (MODE == 1 ? 8 : 2);
  __shared__ __align__(16) unsigned short Asd[BM * BK];
  __shared__ __align__(16) unsigned short Bsd[BN * BK];
  int bx = blockIdx.x, by = blockIdx.y;
  int tid = threadIdx.x;
  int wid = tid >> 6, lane = tid & 63;
  int wr = wid >> 1, wc = wid & 1;

  f32x4 acc[4][4];
  for (int i = 0; i < 4; ++i)
    for (int j = 0; j < 4; ++j) acc[i][j] = (f32x4)0.f;

  const unsigned short* Abase = A + (size_t)by * BM * As;
  const unsigned short* Bbase = B + (size_t)bx * BN * Bs + (MODE == 2 ? (size_t)by * 512 * 128 : 0);

  for (int kt = 0; kt < KT; ++kt) {
    for (int j = 0; j < 4; ++j) {
      int c = tid + j * 256;
      int r = c >> 3, c16 = c & 7;
      int sk = c16 ^ (r & 7);
      gload16(Abase + (size_t)r * As + kt * BK + sk * 8, (char*)Asd + c * 16);
      gload16(Bbase + (size_t)r * Bs + kt * BK + sk * 8, (char*)Bsd + c * 16);
    }
    __syncthreads();
    for (int ks = 0; ks < 2; ++ks) {
      short8 af[4], bf[4];
      int kc = ks * 4 + (lane >> 4);
      for (int i = 0; i < 4; ++i) {
        int r = wr * 64 + i * 16 + (lane & 15);
        af[i] = *(const short8*)((const char*)Asd + r * 128 + ((kc ^ (r & 7)) * 16));
      }
      for (int j = 0; j < 4; ++j) {
        int r = wc * 64 + j * 16 + (lane & 15);
        bf[j] = *(const short8*)((const char*)Bsd + r * 128 + ((kc ^ (r & 7)) * 16));
      }
      for (int i = 0; i < 4; ++i)
        for (int j = 0; j < 4; ++j) {
          if constexpr (MODE == 0)
            acc[i][j] = __builtin_amdgcn_mfma_f32_16x16x32_bf16(af[i], bf[j], acc[i][j], 0, 0, 0);
          else
            acc[i][j] = __builtin_amdgcn_mfma_f32_16x16x32_f16(
                __builtin_bit_cast(half8v, af[i]), __builtin_bit_cast(half8v, bf[j]), acc[i][j], 0, 0, 0);
        }
    }
    __syncthreads();
  }

  int rl = lane >> 4, cl = lane & 15;
  for (int j = 0; j < 4; ++j) {
    int gn = bx * BN + wc * 64 + j * 16 + cl;
    for (int i = 0; i < 4; ++i) {
      for (int q = 0; q < 4; ++q) {
        int gm = by * BM + wr * 64 + i * 16 + rl * 4 + q;
        float v = acc[i][j][q];
        if constexpr (MODE == 0) {
          Cout[(size_t)gm * 512 + gn] = f16bits(v + bias[gn]);
        } else if constexpr (MODE == 1) {
          int bb = gm >> 7, s = gm & 127;
          Cout[(((size_t)(bb * 16 + (s >> 3)) * 512) + gn) * 8 + (s & 7)] = f16bits(v);
        } else {
          int tt = gm & 127, bb = gm >> 7;
          Cout[((size_t)tt * 64 + bb) * KX + 768 + gn] = f2bf(v);
        }
      }
    }
  }
}

// ---------- k_recur: sequential part only ----------
__global__ __launch_bounds__(1024) void k_recur(
    const float* __restrict__ We1,     // [1024][20]
    const float* __restrict__ be1,
    const float* __restrict__ We2,
    const float* __restrict__ be2,
    const uint4* __restrict__ W2,      // Wr hid part, chunked, 32768 uint4
    const uint4* __restrict__ encW2,   // [64*16*512] uint4
    const unsigned short* __restrict__ Remb, // f16 [8192][512] (brnn folded)
    const float* __restrict__ E1g,     // [64][128][20]
    unsigned short* __restrict__ X,    // [8192][1280] bf16
    float* __restrict__ wout)          // [64][128][128]
{
  __shared__ float E1r[SLEN][HE];
  __shared__ uint32_t w1p[HE][257];    // f16-pair We1 dec part, padded stride
  __shared__ float edec[HE];
  __shared__ float ew[SLEN];
  __shared__ uint32_t wpair[SLEN / 2];
  __shared__ uint32_t hpair[DECD / 2];
  __shared__ float ph[2][DECD];
  __shared__ float pc[2][DECD];
  __shared__ float be1s[HE], w2s[HE];
  __shared__ float be2s;

  int b = blockIdx.x, tid = threadIdx.x;

  for (int i = tid; i < SLEN * HE; i += 1024) E1r[i / HE][i % HE] = E1g[(size_t)b * SLEN * HE + i];
  for (int i = tid; i < HE * 256; i += 1024) {
    int h = i >> 8, p = i & 255;
    w1p[h][p] = pkh2(We1[(size_t)(ENCD + 2 * p) * HE + h],
                     We1[(size_t)(ENCD + 2 * p + 1) * HE + h]);
  }
  for (int i = tid; i < DECD / 2; i += 1024) hpair[i] = 0;
  if (tid < HE) { be1s[tid] = be1[tid]; w2s[tid] = We2[tid]; }
  if (tid == 0) be2s = be2[0];
  __syncthreads();

  const int n = tid & 511, hh = tid >> 9;
  const uint4* Wp = W2 + (size_t)hh * 32 * 512 + n;
  const uint4* Ep = encW2 + ((size_t)b * 16 + hh * 8) * 512 + n;
  const uint4* hp4 = (const uint4*)hpair + hh * 32;
  const uint4* wp4 = (const uint4*)wpair + hh * 8;

  for (int t = 0; t < TLEN; ++t) {
    int rowr = t * BATCH + b;

    // prefetch Remb + first 8 weight chunks
    float rpre = 0.f;
    if (tid < 512) {
      union { unsigned short u; _Float16 f; } c;
      c.u = Remb[(size_t)rowr * 512 + tid];
      rpre = (float)c.f;
    }
    uint4 wpre[8];
    #pragma unroll
    for (int i = 0; i < 8; ++i) wpre[i] = Wp[(size_t)i * 512];

    // P1: e_dec[h] = be1[h] + hid . We1_dec[:,h]  (waves 0..9)
    if (tid < 640) {
      int h = tid >> 5, kg = tid & 31;
      float p = 0.f;
      #pragma unroll
      for (int q = 0; q < 8; ++q) {
        int qq = kg * 8 + ((q + kg) & 7);
        p = fdot2(w1p[h][qq], hpair[qq], p);
      }
      p += __shfl_xor(p, 1);  p += __shfl_xor(p, 2);
      p += __shfl_xor(p, 4);  p += __shfl_xor(p, 8);
      p += __shfl_xor(p, 16);
      if (kg == 0) edec[h] = p + be1s[h];
    }
    __syncthreads();

    // P2: scores -> ew[s]
    {
      int s = tid >> 3, sub = tid & 7;
      float p = 0.f;
      if (sub < 5) {
        #pragma unroll
        for (int q = 0; q < 4; ++q) {
          int h = sub * 4 + q;
          p += eluf(E1r[s][h] + edec[h]) * w2s[h];
        }
      }
      p += __shfl_xor(p, 1);
      p += __shfl_xor(p, 2);
      p += __shfl_xor(p, 4);
      if (sub == 0) ew[s] = expf(eluf(p + be2s));
    }
    __syncthreads();

    // P3: softmax + wpair + wout (wave 0 only)
    if (tid < 64) {
      float v = ew[tid] + ew[tid + 64];
      #pragma unroll
      for (int o = 32; o; o >>= 1) v += __shfl_xor(v, o);
      float inv = 1.f / v;
      float w0 = ew[2 * tid] * inv, w1 = ew[2 * tid + 1] * inv;
      wpair[tid] = pkh2(w0, w1);
      float2 wv = { w0, w1 };
      *(float2*)(wout + ((size_t)b * TLEN + t) * SLEN + 2 * tid) = wv;
    }
    __syncthreads();

    // P4: matvecs. rnn_hid: hid @ Wr_hid ; rnn_ctx: w @ encWr
    {
      float a0 = 0, a1 = 0, a2 = 0, a3 = 0;
      #pragma unroll
      for (int i = 0; i < 8; ++i) {
        uint4 wv = wpre[i]; uint4 xv = hp4[i];
        a0 = fdot2(wv.x, xv.x, a0); a1 = fdot2(wv.y, xv.y, a1);
        a2 = fdot2(wv.z, xv.z, a2); a3 = fdot2(wv.w, xv.w, a3);
      }
      #pragma unroll
      for (int i = 8; i < 32; ++i) {
        uint4 wv = Wp[(size_t)i * 512]; uint4 xv = hp4[i];
        a0 = fdot2(wv.x, xv.x, a0); a1 = fdot2(wv.y, xv.y, a1);
        a2 = fdot2(wv.z, xv.z, a2); a3 = fdot2(wv.w, xv.w, a3);
      }
      ph[hh][n] = (a0 + a1) + (a2 + a3);

      float c0 = 0, c1 = 0, c2 = 0, c3 = 0;
      #pragma unroll
      for (int i = 0; i < 8; ++i) {
        uint4 ev = Ep[(size_t)i * 512]; uint4 wv = wp4[i];
        c0 = fdot2(ev.x, wv.x, c0); c1 = fdot2(ev.y, wv.y, c1);
        c2 = fdot2(ev.z, wv.z, c2); c3 = fdot2(ev.w, wv.w, c3);
      }
      pc[hh][n] = (c0 + c1) + (c2 + c3);
    }
    __syncthreads();

    // P5: combine -> new hid, write X hid part, rebuild hpair
    if (tid < 512) {
      float v = rpre + ph[0][n] + ph[1][n] + pc[0][n] + pc[1][n];
      float aa = eluf(v);
      X[(size_t)rowr * KX + 256 + n] = f2bf(aa);
      float bb = __shfl_down(aa, 1);
      if ((n & 1) == 0) hpair[n >> 1] = pkh2(aa, bb);
    }
    __syncthreads();
  }
}

// ---------- k_gemm: out = elu(X @ WoT^T + b_out), M=8192 N=8000 K=1280 ----------
__global__ __launch_bounds__(256) void k_gemm(
    const unsigned short* __restrict__ Xb,
    const unsigned short* __restrict__ WoT,
    const float* __restrict__ bout,
    float* __restrict__ out)
{
  __shared__ __align__(16) unsigned short As[BM * BK];
  __shared__ __align__(16) unsigned short Bs[BN * BK];
  int bx = blockIdx.x;
  int by = blockIdx.y;
  int tid = threadIdx.x;
  int wid = tid >> 6, lane = tid & 63;
  int wr = wid >> 1, wc = wid & 1;

  f32x4 acc[4][4];
  for (int i = 0; i < 4; ++i)
    for (int j = 0; j < 4; ++j) acc[i][j] = (f32x4)0.f;

  const unsigned short* Abase = Xb + (size_t)by * BM * KX;
  const unsigned short* Bbase = WoT + (size_t)bx * BN * KX;

  for (int kt = 0; kt < KX / BK; ++kt) {
    for (int j = 0; j < 4; ++j) {
      int c = tid + j * 256;
      int r = c >> 3, c16 = c & 7;
      int sk = c16 ^ (r & 7);
      gload16(Abase + (size_t)r * KX + kt * BK + sk * 8, (char*)As + c * 16);
      gload16(Bbase + (size_t)r * KX + kt * BK + sk * 8, (char*)Bs + c * 16);
    }
    __syncthreads();
    for (int ks = 0; ks < 2; ++ks) {
      short8 af[4], bf[4];
      int kc = ks * 4 + (lane >> 4);
      for (int i = 0; i < 4; ++i) {
        int r = wr * 64 + i * 16 + (lane & 15);
        af[i] = *(const short8*)((const char*)As + r * 128 + ((kc ^ (r & 7)) * 16));
      }
      for (int j = 0; j < 4; ++j) {
        int r = wc * 64 + j * 16 + (lane & 15);
        bf[j] = *(const short8*)((const char*)Bs + r * 128 + ((kc ^ (r & 7)) * 16));
      }
      for (int i = 0; i < 4; ++i)
        for (int j = 0; j < 4; ++j)
          acc[i][j] = __builtin_amdgcn_mfma_f32_16x16x32_bf16(af[i], bf[j], acc[i][j], 0, 0, 0);
    }
    __syncthreads();
  }

  int rl = lane >> 4, cl = lane & 15;
  for (int j = 0; j < 4; ++j) {
    int gn = bx * BN + wc * 64 + j * 16 + cl;
    if (gn >= VOC) continue;
    float bv = bout[gn];
    for (int i = 0; i < 4; ++i) {
      for (int q = 0; q < 4; ++q) {
        int gm = by * BM + wr * 64 + i * 16 + rl * 4 + q;
        int tt = gm >> 6, bb = gm & 63;
        float v = acc[i][j][q] + bv;
        v = v > 0.f ? v : (expf(v) - 1.f);
        out[((size_t)bb * TLEN + tt) * VOC + gn] = v;
      }
    }
  }
}

// ---------- launch ----------
extern "C" void kernel_launch(void* const* d_in, const int* in_sizes, int n_in,
                              void* d_out, int out_size, void* d_ws, size_t ws_size,
                              hipStream_t stream) {
  const float* enc  = (const float*)d_in[0];
  const int*   ro   = (const int*)d_in[1];
  const float* We1  = (const float*)d_in[2];
  const float* be1  = (const float*)d_in[3];
  const float* We2  = (const float*)d_in[4];
  const float* be2  = (const float*)d_in[5];
  const float* emb  = (const float*)d_in[6];
  const float* Wr   = (const float*)d_in[7];
  const float* brnn = (const float*)d_in[8];
  const float* Wo   = (const float*)d_in[9];
  const float* bo   = (const float*)d_in[10];

  char* ws = (char*)d_ws;
  unsigned short* X     = (unsigned short*)(ws);                 // 20,971,520
  unsigned short* WoT   = (unsigned short*)(ws + 20971520);      // 20,643,840
  unsigned short* W2    = (unsigned short*)(ws + 41615360);      //    524,288
  unsigned short* WembT = (unsigned short*)(ws + 42139648);      //    262,144
  unsigned short* WctxT = (unsigned short*)(ws + 42401792);      //    524,288
  unsigned short* ench  = (unsigned short*)(ws + 42926080);      //  8,388,608  (reused: encTh)
  float*          E1    = (float*)(ws + 51314688);               //    655,360
  unsigned short* Remb  = (unsigned short*)(ws + 51970048);      //  8,388,608  (reused: wh)
  unsigned short* encW2 = (unsigned short*)(ws + 60358656);      //  8,388,608
  unsigned short* encTh = ench;
  unsigned short* wh    = Remb;

  float* outs = (float*)d_out;
  float* wout = (float*)d_out + (size_t)BATCH * TLEN * VOC;

  // parallel precompute
  k_lc     <<<dim3(8192),     256, 0, stream>>>(ro, emb, X);
  k_e1     <<<dim3(2048),     256, 0, stream>>>(enc, We1, E1);
  k_tr_wout<<<dim3(126, 20),  256, 0, stream>>>(Wo, WoT);
  k_tr_w   <<<dim3(8, 4),     256, 0, stream>>>(Wr, WembT, 0, 256, 1);
  k_tr_w   <<<dim3(8, 8),     256, 0, stream>>>(Wr, WctxT, 768, 512, 0);
  k_prep_wr<<<dim3(1024),     256, 0, stream>>>(Wr, W2);
  k_ench   <<<dim3(4096),     256, 0, stream>>>(enc, ench);
  k_gs<0>  <<<dim3(4, 64),    256, 0, stream>>>(X, WembT, brnn, Remb);
  k_gs<1>  <<<dim3(4, 64),    256, 0, stream>>>(ench, WctxT, brnn, encW2);
  // sequential core
  k_recur  <<<dim3(64),      1024, 0, stream>>>(We1, be1, We2, be2,
                                                (const uint4*)W2, (const uint4*)encW2,
                                                Remb, E1, X, wout);
  // post: ctx fill + big GEMM
  k_wh     <<<dim3(1024),     256, 0, stream>>>(wout, wh);
  k_tr_encb<<<dim3(64, 8, 2), 256, 0, stream>>>(enc, encTh);
  k_gs<2>  <<<dim3(4, 64),    256, 0, stream>>>(wh, encTh, brnn, X);
  k_gemm   <<<dim3(63, 64),   256, 0, stream>>>(X, WoT, bo, outs);
  (void)in_sizes; (void)n_in; (void)out_size; (void)ws_size;
}

// Round 4
// 1435.710 us; speedup vs baseline: 4.6878x; 1.4049x over previous
//
#include <hip/hip_runtime.h>
#include <hip/hip_bf16.h>
#include <stdint.h>

#define BATCH 64
#define SLEN 128
#define TLEN 128
#define ENCD 512
#define DECD 512
#define EMBD 256
#define VOC  8000
#define HE   20
#define KX   1280      // EMB + DEC + ENC
#define NPAD 8064      // VOC padded to 63*128

typedef __attribute__((ext_vector_type(8))) short short8;
typedef __attribute__((ext_vector_type(8))) _Float16 half8v;
typedef __attribute__((ext_vector_type(4))) float f32x4;
typedef _Float16 h2 __attribute__((ext_vector_type(2)));

// ---------- helpers ----------
__device__ inline unsigned short f2bf(float f) {
  union { float f; uint32_t u; } v; v.f = f;
  uint32_t r = v.u + 0x7fff + ((v.u >> 16) & 1);
  return (unsigned short)(r >> 16);
}
__device__ inline unsigned short f16bits(float f) {
  union { _Float16 h; unsigned short u; } c; c.h = (_Float16)f; return c.u;
}
__device__ inline uint32_t pkh2(float a, float b) {
  union { h2 h; uint32_t u; } v;
  v.h = h2{(_Float16)a, (_Float16)b};
  return v.u;
}
__device__ inline float fdot2(uint32_t a, uint32_t b, float c) {
#if __has_builtin(__builtin_amdgcn_fdot2)
  union { uint32_t u; h2 h; } x, y; x.u = a; y.u = b;
  return __builtin_amdgcn_fdot2(x.h, y.h, c, false);
#else
  union { uint32_t u; h2 h; } x, y; x.u = a; y.u = b;
  return c + (float)x.h[0] * (float)y.h[0] + (float)x.h[1] * (float)y.h[1];
#endif
}
__device__ inline float eluf(float x) { return x > 0.f ? x : (expf(x) - 1.f); }

typedef const __attribute__((address_space(1))) unsigned int* gptr_t;
typedef __attribute__((address_space(3))) unsigned int* lptr_t;
__device__ inline void gload16(const void* g, void* l) {
  __builtin_amdgcn_global_load_lds((gptr_t)g, (lptr_t)l, 16, 0, 0);
}

// ---------- k_e1: E1t[b][h][s] = enc[b,s,:] @ We1[0:512,h] (transposed store) ----------
__global__ __launch_bounds__(256) void k_e1(const float* __restrict__ enc,
                                            const float* __restrict__ We1,
                                            float* __restrict__ E1) {
  __shared__ float rowbuf[4][ENCD];
  __shared__ float part[4][HE][2];
  int r0 = blockIdx.x * 4;
  int tid = threadIdx.x;
  for (int i = tid; i < 4 * ENCD; i += 256) {
    int rl = i >> 9, e = i & 511;
    rowbuf[rl][e] = enc[(size_t)(r0 + rl) * ENCD + e];
  }
  __syncthreads();
  if (tid < 160) {
    int kg = tid / 80, rem = tid % 80, rl = rem / 20, h = rem % 20;
    float acc = 0.f;
    for (int k = kg * 256; k < kg * 256 + 256; ++k)
      acc += rowbuf[rl][k] * We1[k * HE + h];
    part[rl][h][kg] = acc;
  }
  __syncthreads();
  if (tid < 80) {
    int rl = tid / 20, h = tid % 20;
    int r = r0 + rl, bb = r >> 7, ss = r & 127;
    E1[((size_t)bb * HE + h) * SLEN + ss] = part[rl][h][0] + part[rl][h][1];
  }
}

// ---------- k_tr_wout: W_out [1280][8000] f32 -> WoT [8064][1280] bf16 ----------
__global__ __launch_bounds__(256) void k_tr_wout(const float* __restrict__ Wo,
                                                 unsigned short* __restrict__ WoT) {
  __shared__ float tile[64][65];
  int n0 = blockIdx.x * 64, k0 = blockIdx.y * 64;
  int tid = threadIdx.x;
  for (int i = tid; i < 4096; i += 256) {
    int kk = i >> 6, nn = i & 63;
    int n = n0 + nn;
    tile[kk][nn] = (n < VOC) ? Wo[(size_t)(k0 + kk) * VOC + n] : 0.f;
  }
  __syncthreads();
  for (int i = tid; i < 4096; i += 256) {
    int nn = i >> 6, kk = i & 63;
    WoT[(size_t)(n0 + nn) * KX + k0 + kk] = f2bf(tile[kk][nn]);
  }
}

// ---------- k_tr_w: src rows [k0 .. k0+KN) of [*][512] f32 -> dst [512][KN] ----------
__global__ __launch_bounds__(256) void k_tr_w(const float* __restrict__ src,
                                              unsigned short* __restrict__ dst,
                                              int k0, int KN, int fmt) {
  __shared__ float tile[64][65];
  int n0 = blockIdx.x * 64, kt = blockIdx.y * 64;
  int tid = threadIdx.x;
  for (int i = tid; i < 4096; i += 256) {
    int kk = i >> 6, nn = i & 63;
    tile[kk][nn] = src[(size_t)(k0 + kt + kk) * 512 + n0 + nn];
  }
  __syncthreads();
  for (int i = tid; i < 4096; i += 256) {
    int nn = i >> 6, kk = i & 63;
    float v = tile[kk][nn];
    dst[(size_t)(n0 + nn) * KN + kt + kk] = fmt ? f2bf(v) : f16bits(v);
  }
}

// ---------- k_prep_wr: Wr rows 256..768 -> chunked f16 W2[(h*32+kc)*512+n][8] ----------
__global__ __launch_bounds__(256) void k_prep_wr(const float* __restrict__ Wr,
                                                 unsigned short* __restrict__ W2) {
  int i = blockIdx.x * 256 + threadIdx.x;
  int n = i & 511;
  int j = (i >> 9) & 7;
  int kc = (i >> 12) & 31;
  int h = (i >> 17) & 1;
  int k = h * 256 + kc * 8 + j;
  W2[(((size_t)(h * 32 + kc) * 512) + n) * 8 + j] = f16bits(Wr[(size_t)(256 + k) * 512 + n]);
}

// ---------- k_ench: enc f32 -> f16 flat [8192][512] ----------
__global__ __launch_bounds__(256) void k_ench(const float* __restrict__ enc,
                                              unsigned short* __restrict__ ench) {
  int i = (blockIdx.x * 256 + threadIdx.x) * 4;
  float4 v = *(const float4*)(enc + i);
  ushort4 o = { f16bits(v.x), f16bits(v.y), f16bits(v.z), f16bits(v.w) };
  *(ushort4*)(ench + i) = o;
}

// ---------- k_wh: wout f32 [8192][128] -> f16 ----------
__global__ __launch_bounds__(256) void k_wh(const float* __restrict__ wout,
                                            unsigned short* __restrict__ wh) {
  int i = (blockIdx.x * 256 + threadIdx.x) * 4;
  float4 v = *(const float4*)(wout + i);
  ushort4 o = { f16bits(v.x), f16bits(v.y), f16bits(v.z), f16bits(v.w) };
  *(ushort4*)(wh + i) = o;
}

// ---------- k_tr_encb: enc [b][s][e] f32 -> encTh [b][e][s] f16 ----------
__global__ __launch_bounds__(256) void k_tr_encb(const float* __restrict__ enc,
                                                 unsigned short* __restrict__ encT) {
  __shared__ float tile[64][65];
  int b = blockIdx.x, e0 = blockIdx.y * 64, s0 = blockIdx.z * 64;
  int tid = threadIdx.x;
  const float* eb = enc + (size_t)b * SLEN * ENCD;
  for (int i = tid; i < 4096; i += 256) {
    int ss = i >> 6, ee = i & 63;
    tile[ss][ee] = eb[(size_t)(s0 + ss) * ENCD + e0 + ee];
  }
  __syncthreads();
  unsigned short* ob = encT + (size_t)b * ENCD * SLEN;
  for (int i = tid; i < 4096; i += 256) {
    int ee = i >> 6, ss = i & 63;
    ob[(size_t)(e0 + ee) * SLEN + s0 + ss] = f16bits(tile[ss][ee]);
  }
}

// ---------- k_lc: X[t*B+b][0:256] = bf16(emb[lc]) ----------
__global__ __launch_bounds__(256) void k_lc(const int* __restrict__ ro,
                                            const float* __restrict__ emb,
                                            unsigned short* __restrict__ X) {
  int r = blockIdx.x;
  int t = r >> 6, b = r & 63;
  int lc = (t == 0) ? 0 : ro[b * TLEN + t - 1];
  lc = ((lc % VOC) + VOC) % VOC;
  X[(size_t)r * KX + threadIdx.x] = f2bf(emb[(size_t)lc * EMBD + threadIdx.x]);
}

// ---------- k_gs<MODE>: 128x128xK MFMA GEMM ----------
#define BM 128
#define BN 128
#define BK 64

template<int MODE>
__global__ __launch_bounds__(256) void k_gs(
    const unsigned short* __restrict__ A,
    const unsigned short* __restrict__ B,
    const float* __restrict__ bias,
    unsigned short* __restrict__ Cout)
{
  constexpr int As = (MODE == 0) ? KX : (MODE == 1 ? 512 : 128);
  constexpr int Bs = (MODE == 0) ? 256 : (MODE == 1 ? 512 : 128);
  constexpr int KT = (MODE == 0) ? 4 : (MODE == 1 ? 8 : 2);
  __shared__ __align__(16) unsigned short Asd[BM * BK];
  __shared__ __align__(16) unsigned short Bsd[BN * BK];
  int bx = blockIdx.x, by = blockIdx.y;
  int tid = threadIdx.x;
  int wid = tid >> 6, lane = tid & 63;
  int wr = wid >> 1, wc = wid & 1;

  f32x4 acc[4][4];
  for (int i = 0; i < 4; ++i)
    for (int j = 0; j < 4; ++j) acc[i][j] = (f32x4)0.f;

  const unsigned short* Abase = A + (size_t)by * BM * As;
  const unsigned short* Bbase = B + (size_t)bx * BN * Bs + (MODE == 2 ? (size_t)by * 512 * 128 : 0);

  for (int kt = 0; kt < KT; ++kt) {
    for (int j = 0; j < 4; ++j) {
      int c = tid + j * 256;
      int r = c >> 3, c16 = c & 7;
      int sk = c16 ^ (r & 7);
      gload16(Abase + (size_t)r * As + kt * BK + sk * 8, (char*)Asd + c * 16);
      gload16(Bbase + (size_t)r * Bs + kt * BK + sk * 8, (char*)Bsd + c * 16);
    }
    __syncthreads();
    for (int ks = 0; ks < 2; ++ks) {
      short8 af[4], bf[4];
      int kc = ks * 4 + (lane >> 4);
      for (int i = 0; i < 4; ++i) {
        int r = wr * 64 + i * 16 + (lane & 15);
        af[i] = *(const short8*)((const char*)Asd + r * 128 + ((kc ^ (r & 7)) * 16));
      }
      for (int j = 0; j < 4; ++j) {
        int r = wc * 64 + j * 16 + (lane & 15);
        bf[j] = *(const short8*)((const char*)Bsd + r * 128 + ((kc ^ (r & 7)) * 16));
      }
      for (int i = 0; i < 4; ++i)
        for (int j = 0; j < 4; ++j) {
          if constexpr (MODE == 0)
            acc[i][j] = __builtin_amdgcn_mfma_f32_16x16x32_bf16(af[i], bf[j], acc[i][j], 0, 0, 0);
          else
            acc[i][j] = __builtin_amdgcn_mfma_f32_16x16x32_f16(
                __builtin_bit_cast(half8v, af[i]), __builtin_bit_cast(half8v, bf[j]), acc[i][j], 0, 0, 0);
        }
    }
    __syncthreads();
  }

  int rl = lane >> 4, cl = lane & 15;
  for (int j = 0; j < 4; ++j) {
    int gn = bx * BN + wc * 64 + j * 16 + cl;
    for (int i = 0; i < 4; ++i) {
      for (int q = 0; q < 4; ++q) {
        int gm = by * BM + wr * 64 + i * 16 + rl * 4 + q;
        float v = acc[i][j][q];
        if constexpr (MODE == 0) {
          Cout[(size_t)gm * 512 + gn] = f16bits(v + bias[gn]);
        } else if constexpr (MODE == 1) {
          int bb = gm >> 7, s = gm & 127;
          Cout[(((size_t)(bb * 16 + (s >> 3)) * 512) + gn) * 8 + (s & 7)] = f16bits(v);
        } else {
          int tt = gm & 127, bb = gm >> 7;
          Cout[((size_t)tt * 64 + bb) * KX + 768 + gn] = f2bf(v);
        }
      }
    }
  }
}

// ---------- k_recur: async role-split recurrence ----------
// waves 0..14: stream W2, accumulate hid@W2 partials (phase A)
// wave 15:     full attention chain in-wave (phase A)
// all:         barrier; ctx from LDS + combine (phase B); barrier
__global__ __launch_bounds__(1024) void k_recur(
    const float* __restrict__ We1,     // [1024][20]
    const float* __restrict__ be1,
    const float* __restrict__ We2,
    const float* __restrict__ be2,
    const uint4* __restrict__ W2,      // chunked f16, 32768 uint4
    const uint4* __restrict__ encW2,   // [64][16][512] uint4
    const unsigned short* __restrict__ Remb, // f16 [8192][512] (brnn folded)
    const float* __restrict__ E1g,     // [64][20][128]
    unsigned short* __restrict__ X,    // [8192][1280] bf16
    float* __restrict__ wout)          // [64][128][128]
{
  __shared__ __align__(16) uint4 el[16][512];   // 128 KB: encW2 slice (static)
  __shared__ uint32_t E1p[HE][SLEN / 2];        // 5 KB (f16 pairs)
  __shared__ uint32_t w1p[HE][257];             // 20.6 KB
  __shared__ uint32_t hpair[DECD / 2];          // 1 KB
  __shared__ uint32_t wpairS[SLEN / 2];         // 256 B
  __shared__ float ph[2][DECD];                 // 4 KB
  __shared__ float be1s[HE], w2s[HE];
  __shared__ float be2s;

  int b = blockIdx.x, tid = threadIdx.x;

  for (int i = tid; i < 16 * 512; i += 1024) ((uint4*)el)[i] = encW2[(size_t)b * 8192 + i];
  for (int i = tid; i < HE * (SLEN / 2); i += 1024) {
    int h = i >> 6, p = i & 63;
    const float* ebase = E1g + ((size_t)b * HE + h) * SLEN;
    ((uint32_t*)E1p)[i] = pkh2(ebase[2 * p], ebase[2 * p + 1]);
  }
  for (int i = tid; i < HE * 256; i += 1024) {
    int h = i >> 8, p = i & 255;
    w1p[h][p] = pkh2(We1[(size_t)(ENCD + 2 * p) * HE + h],
                     We1[(size_t)(ENCD + 2 * p + 1) * HE + h]);
  }
  for (int i = tid; i < DECD / 2; i += 1024) hpair[i] = 0;
  for (int i = tid; i < DECD; i += 1024) { ph[0][i] = 0.f; ph[1][i] = 0.f; }
  if (tid < HE) { be1s[tid] = be1[tid]; w2s[tid] = We2[tid]; }
  if (tid == 0) be2s = be2[0];
  __syncthreads();

  const int lane = tid & 63;
  const bool attn_wave = (tid >= 960);
  int mn, mh0, mblocks;
  if (tid < 448)      { mn = tid;              mh0 = 0; mblocks = 4; }
  else if (tid < 896) { mn = tid - 448;        mh0 = 1; mblocks = 4; }
  else if (tid < 960) { mn = 448 + (tid - 896); mh0 = 0; mblocks = 8; }  // full col
  else                { mn = 0;                mh0 = 0; mblocks = 0; }
  const uint4* Wp = W2 + (size_t)(mh0 * 32) * 512 + mn;
  const uint4* hp4 = (const uint4*)hpair;
  const int hbase = mh0 * 32;

  // attention lane roles
  int ah = lane % 20, aseg = lane / 20;
  int q0 = aseg * 86;
  int q1 = (aseg == 2) ? 256 : q0 + 86;
  if (aseg >= 3) { q0 = 0; q1 = 0; }

  for (int t = 0; t < TLEN; ++t) {
    const int rowr = t * BATCH + b;
    float rpre = 0.f;

    if (!attn_wave) {
      // ---------- phase A: hid @ W2 (streamed, 8-deep pipeline) ----------
      if (tid < 512) {
        union { unsigned short u; _Float16 f; } c;
        c.u = Remb[(size_t)rowr * 512 + tid];
        rpre = (float)c.f;
      }
      float a0 = 0, a1 = 0, a2 = 0, a3 = 0;
      uint4 cb[8], nb[8];
      #pragma unroll
      for (int j = 0; j < 8; ++j) cb[j] = Wp[(size_t)j * 512];
      for (int blk = 0; blk < mblocks; ++blk) {
        if (blk + 1 < mblocks) {
          #pragma unroll
          for (int j = 0; j < 8; ++j) nb[j] = Wp[(size_t)((blk + 1) * 8 + j) * 512];
        }
        #pragma unroll
        for (int j = 0; j < 8; ++j) {
          uint4 wv = cb[j]; uint4 xv = hp4[hbase + blk * 8 + j];
          a0 = fdot2(wv.x, xv.x, a0); a1 = fdot2(wv.y, xv.y, a1);
          a2 = fdot2(wv.z, xv.z, a2); a3 = fdot2(wv.w, xv.w, a3);
        }
        #pragma unroll
        for (int j = 0; j < 8; ++j) cb[j] = nb[j];
      }
      ph[mh0][mn] = (a0 + a1) + (a2 + a3);
    } else {
      // ---------- phase A: attention chain, single wave ----------
      float p0 = 0, p1 = 0;
      for (int q = q0; q < q1; q += 2) {
        p0 = fdot2(w1p[ah][q], hpair[q], p0);
        p1 = fdot2(w1p[ah][q + 1], hpair[q + 1], p1);
      }
      float p = p0 + p1;
      float pa = __shfl(p, lane + 20);
      float pb = __shfl(p, lane + 40);
      float edv = p + pa + pb + ((lane < HE) ? be1s[lane] : 0.f);
      // scores for s = 2*lane, 2*lane+1
      float e0a = 0.f, e1a = 0.f;
      #pragma unroll
      for (int h = 0; h < HE; ++h) {
        union { uint32_t u; h2 hh; } e; e.u = E1p[h][lane];
        float ed = __shfl(edv, h);
        e0a += eluf((float)e.hh[0] + ed) * w2s[h];
        e1a += eluf((float)e.hh[1] + ed) * w2s[h];
      }
      float s0 = expf(eluf(e0a + be2s));
      float s1 = expf(eluf(e1a + be2s));
      float tot = s0 + s1;
      #pragma unroll
      for (int o = 1; o < 64; o <<= 1) tot += __shfl_xor(tot, o);
      float inv = 1.f / tot;
      float w0 = s0 * inv, w1 = s1 * inv;
      wpairS[lane] = pkh2(w0, w1);
      float2 wv2 = { w0, w1 };
      *(float2*)(wout + ((size_t)b * TLEN + t) * SLEN + 2 * lane) = wv2;
    }
    __syncthreads();

    // ---------- phase B: ctx (LDS) + combine ----------
    if (tid < 512) {
      int n = tid;
      float c0 = 0, c1 = 0, c2 = 0, c3 = 0;
      #pragma unroll
      for (int g = 0; g < 16; ++g) {
        uint4 ev = el[g][n];
        uint4 wv = ((const uint4*)wpairS)[g];
        c0 = fdot2(ev.x, wv.x, c0); c1 = fdot2(ev.y, wv.y, c1);
        c2 = fdot2(ev.z, wv.z, c2); c3 = fdot2(ev.w, wv.w, c3);
      }
      float v = rpre + ph[0][n] + ph[1][n] + (c0 + c1) + (c2 + c3);
      float aa = eluf(v);
      X[(size_t)rowr * KX + 256 + n] = f2bf(aa);
      float bb = __shfl_down(aa, 1);
      if (!(n & 1)) hpair[n >> 1] = pkh2(aa, bb);
    }
    __syncthreads();
  }
}

// ---------- k_gemm: out = elu(X @ WoT^T + b_out), M=8192 N=8000 K=1280 ----------
__global__ __launch_bounds__(256) void k_gemm(
    const unsigned short* __restrict__ Xb,
    const unsigned short* __restrict__ WoT,
    const float* __restrict__ bout,
    float* __restrict__ out)
{
  __shared__ __align__(16) unsigned short As[BM * BK];
  __shared__ __align__(16) unsigned short Bs[BN * BK];
  int bx = blockIdx.x;
  int by = blockIdx.y;
  int tid = threadIdx.x;
  int wid = tid >> 6, lane = tid & 63;
  int wr = wid >> 1, wc = wid & 1;

  f32x4 acc[4][4];
  for (int i = 0; i < 4; ++i)
    for (int j = 0; j < 4; ++j) acc[i][j] = (f32x4)0.f;

  const unsigned short* Abase = Xb + (size_t)by * BM * KX;
  const unsigned short* Bbase = WoT + (size_t)bx * BN * KX;

  for (int kt = 0; kt < KX / BK; ++kt) {
    for (int j = 0; j < 4; ++j) {
      int c = tid + j * 256;
      int r = c >> 3, c16 = c & 7;
      int sk = c16 ^ (r & 7);
      gload16(Abase + (size_t)r * KX + kt * BK + sk * 8, (char*)As + c * 16);
      gload16(Bbase + (size_t)r * KX + kt * BK + sk * 8, (char*)Bs + c * 16);
    }
    __syncthreads();
    for (int ks = 0; ks < 2; ++ks) {
      short8 af[4], bf[4];
      int kc = ks * 4 + (lane >> 4);
      for (int i = 0; i < 4; ++i) {
        int r = wr * 64 + i * 16 + (lane & 15);
        af[i] = *(const short8*)((const char*)As + r * 128 + ((kc ^ (r & 7)) * 16));
      }
      for (int j = 0; j < 4; ++j) {
        int r = wc * 64 + j * 16 + (lane & 15);
        bf[j] = *(const short8*)((const char*)Bs + r * 128 + ((kc ^ (r & 7)) * 16));
      }
      for (int i = 0; i < 4; ++i)
        for (int j = 0; j < 4; ++j)
          acc[i][j] = __builtin_amdgcn_mfma_f32_16x16x32_bf16(af[i], bf[j], acc[i][j], 0, 0, 0);
    }
    __syncthreads();
  }

  int rl = lane >> 4, cl = lane & 15;
  for (int j = 0; j < 4; ++j) {
    int gn = bx * BN + wc * 64 + j * 16 + cl;
    if (gn >= VOC) continue;
    float bv = bout[gn];
    for (int i = 0; i < 4; ++i) {
      for (int q = 0; q < 4; ++q) {
        int gm = by * BM + wr * 64 + i * 16 + rl * 4 + q;
        int tt = gm >> 6, bb = gm & 63;
        float v = acc[i][j][q] + bv;
        v = v > 0.f ? v : (expf(v) - 1.f);
        out[((size_t)bb * TLEN + tt) * VOC + gn] = v;
      }
    }
  }
}

// ---------- launch ----------
extern "C" void kernel_launch(void* const* d_in, const int* in_sizes, int n_in,
                              void* d_out, int out_size, void* d_ws, size_t ws_size,
                              hipStream_t stream) {
  const float* enc  = (const float*)d_in[0];
  const int*   ro   = (const int*)d_in[1];
  const float* We1  = (const float*)d_in[2];
  const float* be1  = (const float*)d_in[3];
  const float* We2  = (const float*)d_in[4];
  const float* be2  = (const float*)d_in[5];
  const float* emb  = (const float*)d_in[6];
  const float* Wr   = (const float*)d_in[7];
  const float* brnn = (const float*)d_in[8];
  const float* Wo   = (const float*)d_in[9];
  const float* bo   = (const float*)d_in[10];

  char* ws = (char*)d_ws;
  unsigned short* X     = (unsigned short*)(ws);                 // 20,971,520
  unsigned short* WoT   = (unsigned short*)(ws + 20971520);      // 20,643,840
  unsigned short* W2    = (unsigned short*)(ws + 41615360);      //    524,288
  unsigned short* WembT = (unsigned short*)(ws + 42139648);      //    262,144
  unsigned short* WctxT = (unsigned short*)(ws + 42401792);      //    524,288
  unsigned short* ench  = (unsigned short*)(ws + 42926080);      //  8,388,608  (reused: encTh)
  float*          E1    = (float*)(ws + 51314688);               //    655,360
  unsigned short* Remb  = (unsigned short*)(ws + 51970048);      //  8,388,608  (reused: wh)
  unsigned short* encW2 = (unsigned short*)(ws + 60358656);      //  8,388,608
  unsigned short* encTh = ench;
  unsigned short* wh    = Remb;

  float* outs = (float*)d_out;
  float* wout = (float*)d_out + (size_t)BATCH * TLEN * VOC;

  // parallel precompute
  k_lc     <<<dim3(8192),     256, 0, stream>>>(ro, emb, X);
  k_e1     <<<dim3(2048),     256, 0, stream>>>(enc, We1, E1);
  k_tr_wout<<<dim3(126, 20),  256, 0, stream>>>(Wo, WoT);
  k_tr_w   <<<dim3(8, 4),     256, 0, stream>>>(Wr, WembT, 0, 256, 1);
  k_tr_w   <<<dim3(8, 8),     256, 0, stream>>>(Wr, WctxT, 768, 512, 0);
  k_prep_wr<<<dim3(1024),     256, 0, stream>>>(Wr, W2);
  k_ench   <<<dim3(4096),     256, 0, stream>>>(enc, ench);
  k_gs<0>  <<<dim3(4, 64),    256, 0, stream>>>(X, WembT, brnn, Remb);
  k_gs<1>  <<<dim3(4, 64),    256, 0, stream>>>(ench, WctxT, brnn, encW2);
  // sequential core
  k_recur  <<<dim3(64),      1024, 0, stream>>>(We1, be1, We2, be2,
                                                (const uint4*)W2, (const uint4*)encW2,
                                                Remb, E1, X, wout);
  // post: ctx fill + big GEMM
  k_wh     <<<dim3(1024),     256, 0, stream>>>(wout, wh);
  k_tr_encb<<<dim3(64, 8, 2), 256, 0, stream>>>(enc, encTh);
  k_gs<2>  <<<dim3(4, 64),    256, 0, stream>>>(wh, encTh, brnn, X);
  k_gemm   <<<dim3(63, 64),   256, 0, stream>>>(X, WoT, bo, outs);
  (void)in_sizes; (void)n_in; (void)out_size; (void)ws_size;
}